// Round 7
// baseline (143.303 us; speedup 1.0000x reference)
//
#include <hip/hip_runtime.h>
#include <hip/hip_bf16.h>

// NT-Xent loss, MI355X. B=4096, C=512, N=8192, tau=0.1.
// ws layout: [0, 8MB)            bf16 normalized Z (ushort[8192*512])
//            [8MB, 8MB+32KB)     float rowsum[8192]
//            [8MB+32KB, +16KB)   float pos10[4096]  (pos_dot/tau, exact fp32)

#define BDIM 4096
#define CDIM 512
#define NROWS 8192
#define NTILE 32   // 8192 / 256
#define NBLK 528   // NTILE*(NTILE+1)/2 triangular tiles
#define NKT 8      // K-tiles: 512 / 64

typedef __attribute__((ext_vector_type(4))) float f32x4;
typedef __attribute__((ext_vector_type(8))) short bf16x8;

#define AS1 __attribute__((address_space(1)))
#define AS3 __attribute__((address_space(3)))

__device__ __forceinline__ unsigned short f2bf_rne(float x) {
    unsigned u = __float_as_uint(x);
    u += 0x7fffu + ((u >> 16) & 1u);
    return (unsigned short)(u >> 16);
}

// ------- kernel 1: L2-normalize -> bf16, exact positive dot, zero rowsum/out -------
__global__ __launch_bounds__(256) void normalize_kernel(
    const float* __restrict__ z1, const float* __restrict__ z2,
    unsigned short* __restrict__ zb, float* __restrict__ pos10,
    float* __restrict__ rowsum, float* __restrict__ out) {
    if (blockIdx.x == 0) {  // fused zero-init (stream order makes it visible to k2/k3)
#pragma unroll
        for (int i = 0; i < NROWS / 256; ++i) rowsum[i * 256 + threadIdx.x] = 0.f;
        if (threadIdx.x == 0) out[0] = 0.f;
    }
    const int w = threadIdx.x >> 6, lane = threadIdx.x & 63;
    const int r = blockIdx.x * 4 + w;  // pair index 0..4095
    const float4* p1 = (const float4*)(z1 + (size_t)r * CDIM);
    const float4* p2 = (const float4*)(z2 + (size_t)r * CDIM);
    float4 a0 = p1[lane], a1 = p1[64 + lane];
    float4 b0 = p2[lane], b1 = p2[64 + lane];
    float s1 = a0.x * a0.x + a0.y * a0.y + a0.z * a0.z + a0.w * a0.w +
               a1.x * a1.x + a1.y * a1.y + a1.z * a1.z + a1.w * a1.w;
    float s2 = b0.x * b0.x + b0.y * b0.y + b0.z * b0.z + b0.w * b0.w +
               b1.x * b1.x + b1.y * b1.y + b1.z * b1.z + b1.w * b1.w;
    float d = a0.x * b0.x + a0.y * b0.y + a0.z * b0.z + a0.w * b0.w +
              a1.x * b1.x + a1.y * b1.y + a1.z * b1.z + a1.w * b1.w;
#pragma unroll
    for (int m = 1; m < 64; m <<= 1) {
        s1 += __shfl_xor(s1, m, 64);
        s2 += __shfl_xor(s2, m, 64);
        d += __shfl_xor(d, m, 64);
    }
    const float n1 = fmaxf(sqrtf(s1), 1e-12f);
    const float n2 = fmaxf(sqrtf(s2), 1e-12f);
    const float i1 = 1.0f / n1, i2 = 1.0f / n2;
    ushort4 o;
    ushort4* q1 = (ushort4*)(zb + (size_t)r * CDIM);
    ushort4* q2 = (ushort4*)(zb + (size_t)(r + BDIM) * CDIM);
    o.x = f2bf_rne(a0.x * i1); o.y = f2bf_rne(a0.y * i1);
    o.z = f2bf_rne(a0.z * i1); o.w = f2bf_rne(a0.w * i1);
    q1[lane] = o;
    o.x = f2bf_rne(a1.x * i1); o.y = f2bf_rne(a1.y * i1);
    o.z = f2bf_rne(a1.z * i1); o.w = f2bf_rne(a1.w * i1);
    q1[64 + lane] = o;
    o.x = f2bf_rne(b0.x * i2); o.y = f2bf_rne(b0.y * i2);
    o.z = f2bf_rne(b0.z * i2); o.w = f2bf_rne(b0.w * i2);
    q2[lane] = o;
    o.x = f2bf_rne(b1.x * i2); o.y = f2bf_rne(b1.y * i2);
    o.z = f2bf_rne(b1.z * i2); o.w = f2bf_rne(b1.w * i2);
    q2[64 + lane] = o;
    if (lane == 0) pos10[r] = (d / (n1 * n2)) * 10.0f;
}

// ------- kernel 2: triangular fused exp(Z Z^T / tau) row+col sums -------
// 256x256 tile, BK=64, 8 waves (2M x 4N), per-wave C = 128x64.
// m201-style 8-phase schedule (4 phases/K-tile, 2 K-tiles interleaved in a
// 2-buffer): per phase {ds-read one C-quadrant's frags || stage 1 half-tile
// (2x global_load_lds) -> s_barrier -> setprio(1) 16 MFMA setprio(0) ->
// lgkmcnt(0)+s_barrier}. Counted vmcnt(4) gate once per K-tile (vmcnt(0)
// only at the last). Half-tile stage ledger (WAR-safe: A-halves last read
// in q2, B-halves in q1; every stage >= 1 phase after its region's last
// read, reads drained by the lgkm-fused phase-end barrier):
//   prologue: t0.B0 t0.B1 t0.A0 t0.A1 t1.B0 t1.A0 ; vmcnt(4)
//   (t,q0)->(t+1).B1  (t,q1)->(t+1).A1  (t,q2)->(t+2).B0  (t,q3)->(t+2).A0
__global__ __launch_bounds__(512, 2) void simgemm_kernel(
    const unsigned short* __restrict__ Z, float* __restrict__ rowsum) {
    int by = 0, rem = blockIdx.x;
    while (rem >= NTILE - by) { rem -= NTILE - by; ++by; }
    const int bx = by + rem;
    const bool diag = (bx == by);

    // [buf][half j: 0=A rows0-127, 1=A rows128-255, 2=B rows0-127, 3=B rows128-255]
    __shared__ unsigned short lds[2][4][128 * 64];  // 128 KB

    const int t = threadIdx.x;
    const int lane = t & 63, w = t >> 6;  // 8 waves
    const int wr = w >> 2, wc = w & 3;    // 2 x 4

    f32x4 acc[8][4] = {};

    // staging: pass covers 64 rows; thread t -> row t>>3, 16B col t&7 (pre-swizzled).
    const int srow = t >> 3;                              // 0..63
    const int scolb = (((t & 7) ^ ((t >> 3) & 7)) << 4);  // swizzled src col byte
    const char* Zb = (const char*)Z;
    const size_t apan = ((size_t)(by * 256) << 10);
    const size_t bpan = ((size_t)(bx * 256) << 10);

    // stage half-tile (K-tile T, half J) = 2 x global_load_lds (16B/lane)
#define STG(T, J)                                                                \
    {                                                                            \
        const size_t pb_ = ((J) < 2 ? apan : bpan);                              \
        const char* g0_ = Zb + pb_ +                                             \
            ((size_t)((((J) & 1) * 128) + srow) << 10) + ((T) * 128) + scolb;    \
        char* d0_ = (char*)&lds[(T) & 1][J][0] + w * 1024;                       \
        __builtin_amdgcn_global_load_lds((const AS1 void*)g0_,                   \
                                         (AS3 void*)d0_, 16, 0, 0);              \
        __builtin_amdgcn_global_load_lds((const AS1 void*)(g0_ + (64 << 10)),    \
                                         (AS3 void*)(d0_ + 8192), 16, 0, 0);     \
    }

    // prologue: tile0 fully + tile1's B0,A0
    STG(0, 2); STG(0, 3); STG(0, 0); STG(0, 1); STG(1, 2); STG(1, 0);
    asm volatile("s_waitcnt vmcnt(4)\n\ts_barrier" ::: "memory");  // tile0 resident

    const int arow = lane & 15;
    const int brow0 = (wc & 1) * 64;
    const int klo = (lane >> 4) << 4;
    const int swz = (lane & 7) << 4;

#pragma unroll
    for (int T = 0; T < NKT; ++T) {
        const int buf = T & 1;
        const char* Ab = (const char*)&lds[buf][wr][0];
        const char* Bb = (const char*)&lds[buf][2 + (wc >> 1)][0];
        if (T >= 1) {  // gate: tile T's 4 halves resident (2 newer halves allowed in flight)
            if (T < NKT - 1)
                asm volatile("s_waitcnt vmcnt(4)\n\ts_barrier" ::: "memory");
            else
                asm volatile("s_waitcnt vmcnt(0)\n\ts_barrier" ::: "memory");
        }

        bf16x8 af[4][2], bf[4][2];

        // ---- phase q0: read A mi0-3 + B ni0-1; stage (T+1).B1; MFMA quad (0-3, 0-1)
#pragma unroll
        for (int mi = 0; mi < 4; ++mi)
#pragma unroll
            for (int kk = 0; kk < 2; ++kk)
                af[mi][kk] = *(const bf16x8*)(Ab + (mi * 16 + arow) * 128 +
                                              ((kk * 64 + klo) ^ swz));
#pragma unroll
        for (int ni = 0; ni < 2; ++ni)
#pragma unroll
            for (int kk = 0; kk < 2; ++kk)
                bf[ni][kk] = *(const bf16x8*)(Bb + (brow0 + ni * 16 + arow) * 128 +
                                              ((kk * 64 + klo) ^ swz));
        if (T + 1 < NKT) STG(T + 1, 3);
        asm volatile("s_barrier" ::: "memory");
        __builtin_amdgcn_s_setprio(1);
#pragma unroll
        for (int mi = 0; mi < 4; ++mi)
#pragma unroll
            for (int ni = 0; ni < 2; ++ni)
#pragma unroll
                for (int kk = 0; kk < 2; ++kk)
                    acc[mi][ni] = __builtin_amdgcn_mfma_f32_16x16x32_bf16(
                        af[mi][kk], bf[ni][kk], acc[mi][ni], 0, 0, 0);
        __builtin_amdgcn_s_setprio(0);
        asm volatile("s_waitcnt lgkmcnt(0)\n\ts_barrier" ::: "memory");

        // ---- phase q1: read B ni2-3; stage (T+1).A1; MFMA quad (0-3, 2-3)
#pragma unroll
        for (int ni = 2; ni < 4; ++ni)
#pragma unroll
            for (int kk = 0; kk < 2; ++kk)
                bf[ni][kk] = *(const bf16x8*)(Bb + (brow0 + ni * 16 + arow) * 128 +
                                              ((kk * 64 + klo) ^ swz));
        if (T + 1 < NKT) STG(T + 1, 1);
        asm volatile("s_barrier" ::: "memory");
        __builtin_amdgcn_s_setprio(1);
#pragma unroll
        for (int mi = 0; mi < 4; ++mi)
#pragma unroll
            for (int ni = 2; ni < 4; ++ni)
#pragma unroll
                for (int kk = 0; kk < 2; ++kk)
                    acc[mi][ni] = __builtin_amdgcn_mfma_f32_16x16x32_bf16(
                        af[mi][kk], bf[ni][kk], acc[mi][ni], 0, 0, 0);
        __builtin_amdgcn_s_setprio(0);
        asm volatile("s_waitcnt lgkmcnt(0)\n\ts_barrier" ::: "memory");

        // ---- phase q2: read A mi4-7; stage (T+2).B0; MFMA quad (4-7, 0-1)
#pragma unroll
        for (int mi = 0; mi < 4; ++mi)
#pragma unroll
            for (int kk = 0; kk < 2; ++kk)
                af[mi][kk] = *(const bf16x8*)(Ab + ((mi + 4) * 16 + arow) * 128 +
                                              ((kk * 64 + klo) ^ swz));
        if (T + 2 < NKT) STG(T + 2, 2);
        asm volatile("s_barrier" ::: "memory");
        __builtin_amdgcn_s_setprio(1);
#pragma unroll
        for (int mi = 0; mi < 4; ++mi)
#pragma unroll
            for (int ni = 0; ni < 2; ++ni)
#pragma unroll
                for (int kk = 0; kk < 2; ++kk)
                    acc[mi + 4][ni] = __builtin_amdgcn_mfma_f32_16x16x32_bf16(
                        af[mi][kk], bf[ni][kk], acc[mi + 4][ni], 0, 0, 0);
        __builtin_amdgcn_s_setprio(0);
        asm volatile("s_waitcnt lgkmcnt(0)\n\ts_barrier" ::: "memory");

        // ---- phase q3: no reads; stage (T+2).A0; MFMA quad (4-7, 2-3)
        if (T + 2 < NKT) STG(T + 2, 0);
        asm volatile("s_barrier" ::: "memory");
        __builtin_amdgcn_s_setprio(1);
#pragma unroll
        for (int mi = 0; mi < 4; ++mi)
#pragma unroll
            for (int ni = 2; ni < 4; ++ni)
#pragma unroll
                for (int kk = 0; kk < 2; ++kk)
                    acc[mi + 4][ni] = __builtin_amdgcn_mfma_f32_16x16x32_bf16(
                        af[mi][kk], bf[ni][kk], acc[mi + 4][ni], 0, 0, 0);
        __builtin_amdgcn_s_setprio(0);
        asm volatile("s_waitcnt lgkmcnt(0)\n\ts_barrier" ::: "memory");
    }
#undef STG

    // epilogue. C/D: row = wr*128+mi*16+(lane>>4)*4+j, col = wc*64+ni*16+(lane&15)
    const float SC = 14.4269504088896340736f;  // log2(e)/tau
    const int g = lane >> 4;
    float cs[4] = {0.f, 0.f, 0.f, 0.f};
#pragma unroll
    for (int mi = 0; mi < 8; ++mi) {
        float rs0 = 0.f, rs1 = 0.f, rs2 = 0.f, rs3 = 0.f;
#pragma unroll
        for (int ni = 0; ni < 4; ++ni) {
            f32x4 a = acc[mi][ni];
            const float e0 = exp2f(a[0] * SC);
            const float e1 = exp2f(a[1] * SC);
            const float e2 = exp2f(a[2] * SC);
            const float e3 = exp2f(a[3] * SC);
            rs0 += e0; rs1 += e1; rs2 += e2; rs3 += e3;
            cs[ni] += (e0 + e1) + (e2 + e3);
        }
#pragma unroll
        for (int m = 1; m < 16; m <<= 1) {
            rs0 += __shfl_xor(rs0, m, 64);
            rs1 += __shfl_xor(rs1, m, 64);
            rs2 += __shfl_xor(rs2, m, 64);
            rs3 += __shfl_xor(rs3, m, 64);
        }
        if ((lane & 15) == 0) {
            const int rbase = by * 256 + wr * 128 + mi * 16 + g * 4;
            atomicAdd(&rowsum[rbase + 0], rs0);
            atomicAdd(&rowsum[rbase + 1], rs1);
            atomicAdd(&rowsum[rbase + 2], rs2);
            atomicAdd(&rowsum[rbase + 3], rs3);
        }
    }
    if (!diag) {  // symmetry: off-diagonal tile's col sums -> rows bx*256..
#pragma unroll
        for (int ni = 0; ni < 4; ++ni) {
            float c = cs[ni];
            c += __shfl_xor(c, 16, 64);
            c += __shfl_xor(c, 32, 64);
            if (lane < 16)
                atomicAdd(&rowsum[bx * 256 + wc * 64 + ni * 16 + lane], c);
        }
    }
}

// ------- kernel 3: per-pair loss from rowsum + pos10, reduce to scalar -------
__global__ __launch_bounds__(256) void finalize_kernel(
    const float* __restrict__ rowsum, const float* __restrict__ pos10,
    float* __restrict__ out) {
    __shared__ float sm[4];
    const int w = threadIdx.x >> 6, lane = threadIdx.x & 63;
    const int r = blockIdx.x * 256 + threadIdx.x;  // 0..4095
    const float p10 = pos10[r];
    const float pos = expf(p10);
    float l = (logf(rowsum[r] - pos) - p10) +
              (logf(rowsum[r + BDIM] - pos) - p10);
#pragma unroll
    for (int m = 1; m < 64; m <<= 1) l += __shfl_xor(l, m, 64);
    if (lane == 0) sm[w] = l;
    __syncthreads();
    if (threadIdx.x == 0) {
        const float tot = sm[0] + sm[1] + sm[2] + sm[3];
        atomicAdd(out, tot * (1.0f / ((float)NROWS * (float)BDIM)));
    }
}

extern "C" void kernel_launch(void* const* d_in, const int* in_sizes, int n_in,
                              void* d_out, int out_size, void* d_ws, size_t ws_size,
                              hipStream_t stream) {
    const float* z1 = (const float*)d_in[0];
    const float* z2 = (const float*)d_in[1];
    float* out = (float*)d_out;
    unsigned short* zb = (unsigned short*)d_ws;
    float* rowsum = (float*)((char*)d_ws + (size_t)NROWS * CDIM * 2);
    float* pos10 = rowsum + NROWS;

    normalize_kernel<<<BDIM / 4, 256, 0, stream>>>(z1, z2, zb, pos10, rowsum, out);
    simgemm_kernel<<<NBLK, 512, 0, stream>>>(zb, rowsum);
    finalize_kernel<<<BDIM / 256, 256, 0, stream>>>(rowsum, pos10, out);
}